// Round 5
// baseline (1277.377 us; speedup 1.0000x reference)
//
#include <hip/hip_runtime.h>
#include <stdint.h>

// Conductance-LIF network, persistent event-driven kernel. Round 11.
//
// Ledger: r6=647us best. r7 (poll fast-path + batching, affinity lost)=null.
// r8 (wave-autonomous)=3559: row-parallelism mandatory. r9 (2x gather width)
// =834: +1750cyc/step matches the per-CU L2-throughput model (+86KB/step
// at ~56B/cyc/CU), NOT fixed per-row latency. r10 (register-queue batching)
// =750: QPUSH cndmask chains DOUBLED VALU (13->23%) and lost. Remaining
// unattacked term in r6's 6070cyc/step: max-over-12-waves drain imbalance
// (static wave<->word binding; barrier couples block to slowest wave,
// max12 Poisson(9.6) ~ +70% over mean) plus per-row scalar ctz VALU.
//
// r11 = r6 skeleton (8 slices x 192 cols XCD-affine, 12 waves, wave-owned
// word polling, dbuf LDS partials, ONE barrier, r6 tail+publish protocol)
// with a block-shared dynamic row pool:
//   * arrival -> PARALLEL bit expansion (lane i writes entry at prefix-
//     popcount position; one LDS atomicAdd reserves) ~10 ops/WORD.
//   * entries u16 = (class<<12)|row; class 0=rec-ct0, 1=rec-ct1, 2=FF.
//   * all waves grab 4 rows/CAS (bounded by tail, sentinel 0xFFFF validates
//     reservation-vs-write race), gather as 4 independent float4 loads ->
//     4-deep pipelining with ZERO per-row queue VALU.
//   * drain/wave -> mean (~9.6 rows) + granularity, not max12(Poisson).
//   * polls issued at iteration top, consumed at bottom (RTT under process).
// Termination: dbuf {tail,head,wdone}; wdone==12 => tail final => exit on
// head>=tail. Pool recycled post-barrier (re-sentinel [0,tail) only).
// Global sync protocol BYTE-IDENTICAL to r6 (proven): (tag t+1)<<32 | bits
// in one u64, relaxed agent atomics, time-indexed recpub[32][256][48], tags
// never collide with 0xAAAAAAAA poison, publish-before-poll induction ->
// deadlock-free. Placement never affects correctness (perf heuristic only).

#define ATOMIC_LD(p) __hip_atomic_load((p), __ATOMIC_RELAXED, __HIP_MEMORY_SCOPE_AGENT)
#define LDS_LD(p)    __hip_atomic_load((p), __ATOMIC_RELAXED, __HIP_MEMORY_SCOPE_WORKGROUP)
#define LDS_ST(p, v) __hip_atomic_store((p), (v), __ATOMIC_RELAXED, __HIP_MEMORY_SCOPE_WORKGROUP)

#define ACCW(CLS, W4) do {                                                     \
    if ((CLS) == 0u)      { a0.x += (W4).x; a0.y += (W4).y;                    \
                            a0.z += (W4).z; a0.w += (W4).w; }                  \
    else if ((CLS) == 1u) { a1.x += (W4).x; a1.y += (W4).y;                    \
                            a1.z += (W4).z; a1.w += (W4).w; }                  \
    else                  { aF.x += (W4).x; aF.y += (W4).y;                    \
                            aF.z += (W4).z; aF.w += (W4).w; }                  \
} while (0)

#define QCAP 2308   // worst case 1536 rec + 768 FF = 2304 (+4 pad for wl<4 reads)

__global__ __launch_bounds__(768) void snn_lif_kernel(
    const float* __restrict__ I,     // [32][256][768] input spikes (0/1)
    const float* __restrict__ W,     // [1536][1536] recurrent weights (row = pre)
    const float* __restrict__ WF,    // [768][1536]  FF weights (row = input)
    const float* __restrict__ sf,    // [2][2] scaling (pre ct, post ct)
    const float* __restrict__ sfF,   // [1][2] FF scaling (post ct)
    const int*   __restrict__ ct,    // [1536] cell type 0/1
    float* __restrict__ out,         // spk [32][256][1536] then volt [...]
    uint64_t* __restrict__ recpub)   // [32][256][48]: (tag<<32)|spike-bits
{
    const int tid = threadIdx.x;
    const int j   = blockIdx.x & 7;    // column slice -> XCD under %8 RR (perf)
    const int b   = blockIdx.x >> 3;   // batch
    const int wv  = tid >> 6;          // wave 0..11
    const int wl  = tid & 63;          // lane

    __shared__ float4   part0[2][12][48];   // rec ct0 partials (dbuf)
    __shared__ float4   part1[2][12][48];   // rec ct1 partials
    __shared__ float4   partF[2][12][48];   // FF partials
    __shared__ uint32_t ctm32_sh[48];       // cell-type bits per 32-neuron word
    __shared__ uint16_t queue_sh[2][QCAP];  // row pool (dbuf), 0xFFFF = empty
    __shared__ int      tail_sh[2], head_sh[2], wdone_sh[2];

    // ---- init pool (both buffers) ----
    for (int i = tid; i < QCAP; i += 768) {
        queue_sh[0][i] = 0xFFFFu;
        queue_sh[1][i] = 0xFFFFu;
    }
    if (tid == 0) {
        tail_sh[0] = tail_sh[1] = 0;
        head_sh[0] = head_sh[1] = 0;
        wdone_sh[0] = wdone_sh[1] = 0;
    }

    // ---- cell-type bitmask via block-wide ballots (2 x 768) ----
    for (int r = 0; r < 2; ++r) {
        int c = ct[r * 768 + tid];
        uint64_t bal = __ballot(c != 0);
        if (wl == 0) {
            ctm32_sh[r * 24 + wv * 2]     = (uint32_t)bal;
            ctm32_sh[r * 24 + wv * 2 + 1] = (uint32_t)(bal >> 32);
        }
    }
    __syncthreads();

    uint32_t cmw[4];
    #pragma unroll
    for (int k = 0; k < 4; ++k) cmw[k] = ctm32_sh[wv * 4 + k];

    // ---- owner-neuron constants (threads 0..191 own neuron m) ----
    const int m = j * 192 + ((tid < 192) ? tid : 0);
    const int   myct = ct[m];
    const float s0m  = sf[myct];
    const float s1m  = sf[2 + myct];
    const float sFm  = sfF[myct];
    const float lc   = (myct == 0) ? (1.0f / 200.0f) : (1.0f / 100.0f);
    const float refsteps = (myct == 0) ? 2.0f : 1.0f;
    const float ar0 = expf(-1.0f / 0.5f),  ad0 = expf(-1.0f / 2.0f);
    const float ar1 = expf(-1.0f / 2.0f),  ad1 = expf(-1.0f / 100.0f);
    const float ar2 = expf(-1.0f / 0.5f),  ad2 = expf(-1.0f / 5.0f);
    const float arF = expf(-1.0f / 0.5f),  adF = expf(-1.0f / 2.0f);

    float U = -65.0f, refc = 0.0f;
    float x0 = 0, g0 = 0, x1 = 0, g1 = 0, x2 = 0, g2 = 0, xF = 0, gF = 0;

    const int  btbase = b * 256;
    const bool gl     = (wl < 48);
    const uint32_t colbase = (uint32_t)(j * 192) + (uint32_t)((wl < 48 ? wl : 47) * 4);

    // initial FF mask: wave wv ballots inputs wv*64..+63 of I[b,0,:]
    uint64_t fmask;
    {
        float iv = __builtin_nontemporal_load(
            &I[(uint32_t)btbase * 768u + (uint32_t)tid]);
        fmask = __ballot(iv > 0.5f);
    }

    for (int t = 0; t < 256; ++t) {
        const int buf = t & 1;
        uint16_t*                 qq = &queue_sh[buf][0];
        volatile const uint16_t*  qv = &queue_sh[buf][0];

        // issue the first poll sample EARLY (latency hides under FF expand)
        const uint32_t pbase = (uint32_t)(btbase + t - 1) * 48u + (uint32_t)(wv * 4);
        uint64_t pv0 = 0;
        if (t > 0 && wl < 4)
            pv0 = ATOMIC_LD(&recpub[pbase + (uint32_t)wl]);

        // prefetch next-step input (consumed by the ballot before the barrier)
        float ivn = 0.0f;
        if (t < 255)
            ivn = __builtin_nontemporal_load(
                &I[(uint32_t)(btbase + t + 1) * 768u + (uint32_t)tid]);

        // ---- FF expansion into the pool (class 2), parallel prefix ----
        if (fmask) {
            const int cnt = __builtin_popcountll(fmask);
            int b0 = 0;
            if (wl == 0) b0 = atomicAdd(&tail_sh[buf], cnt);
            b0 = __shfl(b0, 0);
            if ((fmask >> (uint32_t)wl) & 1ull) {
                const uint32_t pos = (uint32_t)__builtin_popcountll(
                    fmask & ((1ull << (uint32_t)wl) - 1ull));
                qq[b0 + (int)pos] = (uint16_t)(0x2000u | (uint32_t)(wv * 64 + wl));
            }
        }

        float4 a0 = make_float4(0.f, 0.f, 0.f, 0.f);
        float4 a1 = a0, aF = a0;

        // ---- drain loop: poll-issue / grab4 / process / poll-consume ----
        uint32_t ready  = (t > 0) ? 0u : 0xFu;
        bool     counted = false;
        bool     havepv  = (t > 0);
        uint64_t pvcur   = pv0;

        for (;;) {
            // (1) issue poll for missing words (consumed at (4))
            if (ready != 0xFu && !havepv) {
                pvcur = 0;
                if (wl < 4) pvcur = ATOMIC_LD(&recpub[pbase + (uint32_t)wl]);
                havepv = true;
            }
            // (2) grab up to 4 rows (lane-0 CAS bounded by tail)
            int got = 0, gbase = 0, term = 0;
            if (wl == 0) {
                const int wd = LDS_LD(&wdone_sh[buf]);
                __threadfence_block();
                int hd = LDS_LD(&head_sh[buf]);
                int tl = LDS_LD(&tail_sh[buf]);
                while (hd < tl) {
                    const int want = (hd + 4 < tl) ? hd + 4 : tl;
                    const int old  = atomicCAS(&head_sh[buf], hd, want);
                    if (old == hd) { got = want - hd; gbase = hd; break; }
                    hd = old;
                    tl = LDS_LD(&tail_sh[buf]);
                }
                if (got == 0 && wd == 12 && hd >= tl) term = 1;
            }
            got = __shfl(got, 0);
            // (3) process grabbed rows: 4 independent float4 loads, one wait
            if (got) {
                gbase = __shfl(gbase, 0);
                uint32_t e0, e1, e2, e3;
                for (;;) {   // sentinel-validate (reservation precedes write)
                    uint32_t ev = 0xFFFFu;
                    if (wl < 4) ev = qv[gbase + wl];
                    e0 = (uint32_t)__builtin_amdgcn_readlane(ev, 0);
                    e1 = (uint32_t)__builtin_amdgcn_readlane(ev, 1);
                    e2 = (uint32_t)__builtin_amdgcn_readlane(ev, 2);
                    e3 = (uint32_t)__builtin_amdgcn_readlane(ev, 3);
                    bool ok = (e0 != 0xFFFFu);
                    if (got > 1 && e1 == 0xFFFFu) ok = false;
                    if (got > 2 && e2 == 0xFFFFu) ok = false;
                    if (got > 3 && e3 == 0xFFFFu) ok = false;
                    if (ok) break;
                }
                if (gl) {
                    const uint32_t r0 = e0 & 0xFFFu, c0 = e0 >> 12;
                    const float4 w0 = *(const float4*)(
                        ((c0 == 2u) ? WF : W) + (size_t)r0 * 1536u + colbase);
                    float4 w1, w2, w3;
                    uint32_t c1 = 0, c2 = 0, c3 = 0;
                    if (got > 1) {
                        const uint32_t r1 = e1 & 0xFFFu; c1 = e1 >> 12;
                        w1 = *(const float4*)(
                            ((c1 == 2u) ? WF : W) + (size_t)r1 * 1536u + colbase);
                    }
                    if (got > 2) {
                        const uint32_t r2 = e2 & 0xFFFu; c2 = e2 >> 12;
                        w2 = *(const float4*)(
                            ((c2 == 2u) ? WF : W) + (size_t)r2 * 1536u + colbase);
                    }
                    if (got > 3) {
                        const uint32_t r3 = e3 & 0xFFFu; c3 = e3 >> 12;
                        w3 = *(const float4*)(
                            ((c3 == 2u) ? WF : W) + (size_t)r3 * 1536u + colbase);
                    }
                    ACCW(c0, w0);
                    if (got > 1) ACCW(c1, w1);
                    if (got > 2) ACCW(c2, w2);
                    if (got > 3) ACCW(c3, w3);
                }
            }
            // (4) consume poll: expand fresh words in parallel
            if (ready != 0xFu && havepv) {
                const uint32_t plo = (uint32_t)pvcur;
                const uint32_t phi = (uint32_t)(pvcur >> 32);
                #pragma unroll
                for (int k = 0; k < 4; ++k) {
                    if (ready & (1u << k)) continue;
                    if ((uint32_t)__builtin_amdgcn_readlane(phi, k) != (uint32_t)t)
                        continue;                      // not published yet
                    ready |= 1u << k;
                    const uint32_t bits = (uint32_t)__builtin_amdgcn_readlane(plo, k);
                    if (bits) {
                        const int cnt = __builtin_popcount(bits);
                        int b0 = 0;
                        if (wl == 0) b0 = atomicAdd(&tail_sh[buf], cnt);
                        b0 = __shfl(b0, 0);
                        if (wl < 32 && ((bits >> (uint32_t)wl) & 1u)) {
                            const uint32_t pos = __builtin_popcount(
                                bits & ((1u << (uint32_t)wl) - 1u));
                            const uint32_t cls = (cmw[k] >> (uint32_t)wl) & 1u;
                            qq[b0 + (int)pos] = (uint16_t)(
                                (cls << 12) |
                                ((uint32_t)(wv * 4 + k) * 32u + (uint32_t)wl));
                        }
                    }
                }
                havepv = false;
            }
            // (5) all my sources in the pool: count once
            if (ready == 0xFu && !counted) {
                __threadfence_block();
                if (wl == 0) atomicAdd(&wdone_sh[buf], 1);
                counted = true;
            }
            // (6) exit: pool final (wdone==12) and fully drained
            if (!got) {
                term = __shfl(term, 0);
                if (term) break;
            }
        }

        // final tail (pool complete) -- needed pre-barrier for the recycle
        const int tfin = LDS_LD(&tail_sh[buf]);

        // ---- write partials ----
        if (gl) {
            part0[buf][wv][wl] = a0;
            part1[buf][wv][wl] = a1;
            partF[buf][wv][wl] = aF;
        }
        fmask = __ballot(ivn > 0.5f);   // FF mask for step t+1 (per-wave reg)
        __syncthreads();                // partials of ALL waves visible

        // ---- tail (threads 0..191): reduce, LIF, publish FIRST, store ----
        if (tid < 192) {
            const float* p0 = (const float*)&part0[buf][0][0];
            const float* p1 = (const float*)&part1[buf][0][0];
            const float* pF = (const float*)&partF[buf][0][0];
            float z0s = 0.f, z1s = 0.f, zFs = 0.f;
            #pragma unroll
            for (int k = 0; k < 12; ++k) {
                z0s += p0[k * 192 + tid];
                z1s += p1[k * 192 + tid];
                zFs += pF[k * 192 + tid];
            }
            z0s *= s0m; z1s *= s1m; zFs *= sFm;
            x0 = ar0 * x0 + z0s;  g0 = ad0 * g0 + x0;   // syn0 (pre ct0)
            x1 = ar1 * x1 + z0s;  g1 = ad1 * g1 + x1;   // syn1 (pre ct0, same z0)
            x2 = ar2 * x2 + z1s;  g2 = ad2 * g2 + x2;   // syn2 (pre ct1)
            xF = arF * xF + zFs;  gF = adF * gF + xF;   // feed-forward
            const float gtot = g0 + 0.5f * g1 + g2 + gF;   // gbar=[1,.5,1], FF 1
            const float gE   = -70.0f * g2;                // gbar*Erev=[0,0,-70], FF 0
            const float Isyn = gE - gtot * U;
            float Un = U + lc * (10.0f * (-65.0f - U) + Isyn);
            if (refc > 0.0f) Un = -65.0f;
            refc = fmaxf(refc - 1.0f, 0.0f);
            const bool s = (Un - (-50.0f)) >= 0.0f;
            // publish ASAP: waves 0..2 cover 64 consecutive neurons each;
            // lanes 0/32 store (tag<<32)|half — flag and data in one word.
            const uint64_t bal = __ballot(s);
            if (wl == 0 || wl == 32) {
                const uint32_t half = (wl == 0) ? (uint32_t)bal : (uint32_t)(bal >> 32);
                const uint32_t word = (uint32_t)(j * 6 + wv * 2) + (wl == 32 ? 1u : 0u);
                const uint32_t widx = (uint32_t)(btbase + t) * 48u + word;
                const uint64_t v = ((uint64_t)(uint32_t)(t + 1) << 32) | half;
                __hip_atomic_store(&recpub[widx], v, __ATOMIC_RELAXED,
                                   __HIP_MEMORY_SCOPE_AGENT);
            }
            const float Uo = s ? -65.0f : Un;
            refc = s ? refsteps : refc;
            U = Uo;
            const uint32_t oidx = (uint32_t)(btbase + t) * 1536u + (uint32_t)m;
            __builtin_nontemporal_store(s ? 1.0f : 0.0f, &out[oidx]);
            __builtin_nontemporal_store(Uo, &out[12582912u + oidx]);
        }

        // ---- recycle this step's pool for reuse at t+2 (post-barrier: all
        // step-t users done; t+2 users cross step-(t+1)'s barrier after this).
        // Only [0, tfin) was written; beyond is still sentinel. ----
        for (int i = tid; i < tfin; i += 768) qq[i] = 0xFFFFu;
        if (tid == 0) {
            LDS_ST(&tail_sh[buf], 0);
            LDS_ST(&head_sh[buf], 0);
            LDS_ST(&wdone_sh[buf], 0);
        }
        // no second barrier: partials & pool double-buffered; no wave reaches
        // step t+2's writes before all waves passed step t+1's barrier.
    }
}

extern "C" void kernel_launch(void* const* d_in, const int* in_sizes, int n_in,
                              void* d_out, int out_size, void* d_ws, size_t ws_size,
                              hipStream_t stream) {
    const float* I   = (const float*)d_in[0];   // input_spikes (32,256,768)
    const float* W   = (const float*)d_in[1];   // weights (1536,1536)
    const float* WF  = (const float*)d_in[2];   // weights_FF (768,1536)
    const float* sf  = (const float*)d_in[3];   // scaling_factors (2,2)
    const float* sfF = (const float*)d_in[4];   // scaling_factors_FF (1,2)
    const int*   ct  = (const int*)d_in[5];     // cell_type_indices (1536)
    // d_in[6] cell_type_indices_FF: all zeros, folded into sfF indexing.

    uint64_t* recpub = (uint64_t*)d_ws;   // 32*256*48*8 = 3,145,728 B

    snn_lif_kernel<<<dim3(256), dim3(768), 0, stream>>>(
        I, W, WF, sf, sfF, ct, (float*)d_out, recpub);
}

// Round 6
// 884.936 us; speedup vs baseline: 1.4435x; 1.4435x over previous
//
#include <hip/hip_runtime.h>
#include <stdint.h>

// Conductance-LIF network, persistent event-driven kernel. Round 12.
//
// Ledger: r6=647us best. r7 (poll fast-path/batch, affinity confound)=null.
// r8 (wave-autonomous)=3559. r9 (2x gather width)=834: L2-throughput model
// confirmed. r10 (reg-queue batching)=750: +857 VALU -> +960 step. r11 (LDS
// dynamic pool)=1196: +2070 VALU -> +2200 step. The 1:1 VALU->step translation
// (r10,r11) + null latency-batching (r7,r10) says: within a CU the 12 waves
// already cover each other's LOAD LATENCY, but instruction issue and L2
// throughput land directly on the step. r6 budget: ~800 VALU + ~1900 L2
// (117KB/step/CU @ ~64B/cyc) = 2700 busy of 6070 -> ~3400 cyc IDLE
// (poll-spin with no arrived work + barrier wait). No round has attacked the
// idle itself.
//
// r12 = r6 VERBATIM structure, but 16 slices x 96 cols -> 512 blocks, so
// EXACTLY 2 blocks (different slice,batch units) co-reside per CU (24 waves;
// 3 blocks impossible at 36>32 waves -> placement forced uniform). The two
// blocks have independent arrival phases: when one block's waves idle-poll,
// the other's drain -> the ~3400 idle cycles get filled with real work.
//   * per-wave structure IDENTICAL to r6: 4 words/wave polled by lanes 0..3,
//     same arrival-ordered drain loop, ~12.75 rows/wave (block still needs
//     all 1536 pre-rows; only column width halved).
//   * gather: 24 lanes x float4 = 384B/row = 3 aligned cache lines (row
//     stride 6144B, colbase j*384B -> 384B-aligned). Lanes 24..63 clamp to
//     lane 23's address (same lines, no extra traffic); LDS writes guarded.
//   * per-CU: VALU x2 (~1600cyc), L2 bytes UNCHANGED (2 x 58.8KB), per-XCD
//     L2 footprint UNCHANGED (blockIdx%8=x -> j in {x,x+8}: same 1.77MB
//     W+WF strip pair L2-resident).
//   * publish: slice j owns words j*3..j*3+2 (16 producers x 3 = 48 words).
// Sync protocol BYTE-IDENTICAL to r6 (proven): flag+data in ONE 64-bit word
// (hi32 = t+1 for step-t spikes, lo32 = 32 spike bits), relaxed agent-scope
// atomics only, time-indexed recpub[32][256][48], tags 1..256 never collide
// with 0xAAAAAAAA ws poison. All 512 blocks co-resident (2/CU exactly);
// publish for step t precedes any wait on step-t words (induction) ->
// deadlock-free. Block->XCD placement is a perf heuristic only, never
// correctness.

#define ATOMIC_LD(p) __hip_atomic_load((p), __ATOMIC_RELAXED, __HIP_MEMORY_SCOPE_AGENT)

__global__ __launch_bounds__(768) void snn_lif_kernel(
    const float* __restrict__ I,     // [32][256][768] input spikes (0/1)
    const float* __restrict__ W,     // [1536][1536] recurrent weights (row = pre)
    const float* __restrict__ WF,    // [768][1536]  FF weights (row = input)
    const float* __restrict__ sf,    // [2][2] scaling (pre ct, post ct)
    const float* __restrict__ sfF,   // [1][2] FF scaling (post ct)
    const int*   __restrict__ ct,    // [1536] cell type 0/1
    float* __restrict__ out,         // spk [32][256][1536] then volt [...]
    uint64_t* __restrict__ recpub)   // [32][256][48]: (tag<<32)|spike-bits
{
    const int tid = threadIdx.x;
    const int j   = blockIdx.x & 15;   // 96-col slice; XCD {j&7} (perf only)
    const int b   = blockIdx.x >> 4;   // batch
    const int wv  = tid >> 6;          // wave 0..11
    const int wl  = tid & 63;          // lane

    __shared__ float4   part0[2][12][24];   // rec ct0 partials (dbuf)
    __shared__ float4   part1[2][12][24];   // rec ct1 partials
    __shared__ float4   partF[2][12][24];   // FF partials
    __shared__ uint32_t ctm32_sh[48];       // cell-type bits per 32-neuron word

    // ---- cell-type bitmask via block-wide ballots (2 x 768) ----
    for (int r = 0; r < 2; ++r) {
        int c = ct[r * 768 + tid];
        uint64_t bal = __ballot(c != 0);
        if (wl == 0) {
            ctm32_sh[r * 24 + wv * 2]     = (uint32_t)bal;
            ctm32_sh[r * 24 + wv * 2 + 1] = (uint32_t)(bal >> 32);
        }
    }
    __syncthreads();

    // hoist this wave's 4 word ct-masks to registers
    uint32_t cmw[4];
    #pragma unroll
    for (int k = 0; k < 4; ++k) cmw[k] = ctm32_sh[wv * 4 + k];

    // ---- owner-neuron constants (threads 0..95 own neuron m) ----
    const int m = j * 96 + ((tid < 96) ? tid : 0);
    const int   myct = ct[m];
    const float s0m  = sf[myct];
    const float s1m  = sf[2 + myct];
    const float sFm  = sfF[myct];
    const float lc   = (myct == 0) ? (1.0f / 200.0f) : (1.0f / 100.0f);
    const float refsteps = (myct == 0) ? 2.0f : 1.0f;
    const float ar0 = expf(-1.0f / 0.5f),  ad0 = expf(-1.0f / 2.0f);
    const float ar1 = expf(-1.0f / 2.0f),  ad1 = expf(-1.0f / 100.0f);
    const float ar2 = expf(-1.0f / 0.5f),  ad2 = expf(-1.0f / 5.0f);
    const float arF = expf(-1.0f / 0.5f),  adF = expf(-1.0f / 2.0f);

    float U = -65.0f, refc = 0.0f;
    float x0 = 0, g0 = 0, x1 = 0, g1 = 0, x2 = 0, g2 = 0, xF = 0, gF = 0;

    const int  btbase = b * 256;
    const bool gl     = (wl < 24);                          // gather/partial lane
    // clamp: lanes 24..63 duplicate lane 23's 16B segment (bytes 368..383 of
    // the 384B row span) -> loads unguarded, zero extra cache lines; LDS
    // partial writes stay gl-guarded.
    const uint32_t colbase = (uint32_t)(j * 96) + (uint32_t)((wl < 24 ? wl : 23) * 4);

    // initial FF mask: wave wv ballots inputs wv*64..+63 of I[b,0,:]
    uint64_t fmask;
    {
        float iv = __builtin_nontemporal_load(
            &I[(uint32_t)btbase * 768u + (uint32_t)tid]);
        fmask = __ballot(iv > 0.5f);
    }

    for (int t = 0; t < 256; ++t) {
        // prefetch next-step input (consumed by the ballot after the gather)
        float ivn = 0.0f;
        if (t < 255)
            ivn = __builtin_nontemporal_load(
                &I[(uint32_t)(btbase + t + 1) * 768u + (uint32_t)tid]);

        float4 a0 = make_float4(0.f, 0.f, 0.f, 0.f);
        float4 a1 = a0, aF = a0;

        // ---- FF rows (always ready; fmask is this wave's own ballot) ----
        {
            uint64_t mm = fmask;   // wave-uniform
            while (mm) {
                const int bit = __builtin_ctzll(mm);
                mm &= mm - 1;
                const uint32_t row = (uint32_t)(wv * 64 + bit);
                const float4 w = *(const float4*)(WF + (size_t)row * 1536u + colbase);
                aF.x += w.x; aF.y += w.y; aF.z += w.z; aF.w += w.w;
            }
        }

        // ---- poll 4 rec words concurrently; gather each on arrival ----
        if (t > 0) {
            uint32_t ready = 0;
            const uint32_t pbase = (uint32_t)(btbase + t - 1) * 48u + (uint32_t)(wv * 4);
            do {
                uint64_t pv = 0;
                if (wl < 4)
                    pv = ATOMIC_LD(&recpub[pbase + (uint32_t)wl]);
                const uint32_t plo = (uint32_t)pv;
                const uint32_t phi = (uint32_t)(pv >> 32);
                #pragma unroll
                for (int k = 0; k < 4; ++k) {
                    if (ready & (1u << k)) continue;
                    const uint32_t tg = (uint32_t)__builtin_amdgcn_readlane(phi, k);
                    if (tg != (uint32_t)t) continue;      // not published yet
                    ready |= 1u << k;
                    uint32_t bits = (uint32_t)__builtin_amdgcn_readlane(plo, k);
                    const uint32_t cm   = cmw[k];
                    const uint32_t word = (uint32_t)(wv * 4 + k);
                    while (bits) {                         // wave-uniform row loop
                        const int bit = __builtin_ctz(bits);
                        bits &= bits - 1;
                        const uint32_t row = word * 32u + (uint32_t)bit;
                        const float4 w = *(const float4*)(W + (size_t)row * 1536u + colbase);
                        if ((cm >> bit) & 1u) {
                            a1.x += w.x; a1.y += w.y; a1.z += w.z; a1.w += w.w;
                        } else {
                            a0.x += w.x; a0.y += w.y; a0.z += w.z; a0.w += w.w;
                        }
                    }
                }
            } while (ready != 0xFu);
        }

        const int buf = t & 1;
        if (gl) {
            part0[buf][wv][wl] = a0;
            part1[buf][wv][wl] = a1;
            partF[buf][wv][wl] = aF;
        }
        fmask = __ballot(ivn > 0.5f);   // FF mask for step t+1 (per-wave register)
        __syncthreads();                // partials of ALL waves visible

        // ---- tail (threads 0..95): reduce, LIF, publish FIRST, store ----
        if (tid < 96) {
            const float* p0 = (const float*)&part0[buf][0][0];
            const float* p1 = (const float*)&part1[buf][0][0];
            const float* pF = (const float*)&partF[buf][0][0];
            float z0s = 0.f, z1s = 0.f, zFs = 0.f;
            #pragma unroll
            for (int k = 0; k < 12; ++k) {
                z0s += p0[k * 96 + tid];
                z1s += p1[k * 96 + tid];
                zFs += pF[k * 96 + tid];
            }
            z0s *= s0m; z1s *= s1m; zFs *= sFm;
            x0 = ar0 * x0 + z0s;  g0 = ad0 * g0 + x0;   // syn0 (pre ct0)
            x1 = ar1 * x1 + z0s;  g1 = ad1 * g1 + x1;   // syn1 (pre ct0, same z0)
            x2 = ar2 * x2 + z1s;  g2 = ad2 * g2 + x2;   // syn2 (pre ct1)
            xF = arF * xF + zFs;  gF = adF * gF + xF;   // feed-forward
            const float gtot = g0 + 0.5f * g1 + g2 + gF;   // gbar=[1,.5,1], FF 1
            const float gE   = -70.0f * g2;                // gbar*Erev=[0,0,-70], FF 0
            const float Isyn = gE - gtot * U;
            float Un = U + lc * (10.0f * (-65.0f - U) + Isyn);
            if (refc > 0.0f) Un = -65.0f;
            refc = fmaxf(refc - 1.0f, 0.0f);
            const bool s = (Un - (-50.0f)) >= 0.0f;
            // publish ASAP. Tail = wave0 (neurons j*96..+63) + wave1 lanes
            // 0..31 (neurons j*96+64..+95). Ballots are per-wave; inactive
            // lanes (tid>=96) contribute 0 and publish nothing.
            const uint64_t bal = __ballot(s);
            if (wv == 0 && (wl == 0 || wl == 32)) {
                const uint32_t half = (wl == 0) ? (uint32_t)bal : (uint32_t)(bal >> 32);
                const uint32_t word = (uint32_t)(j * 3) + (wl == 32 ? 1u : 0u);
                const uint32_t widx = (uint32_t)(btbase + t) * 48u + word;
                const uint64_t v = ((uint64_t)(uint32_t)(t + 1) << 32) | half;
                __hip_atomic_store(&recpub[widx], v, __ATOMIC_RELAXED,
                                   __HIP_MEMORY_SCOPE_AGENT);
            }
            if (wv == 1 && wl == 0) {
                const uint32_t widx = (uint32_t)(btbase + t) * 48u + (uint32_t)(j * 3 + 2);
                const uint64_t v = ((uint64_t)(uint32_t)(t + 1) << 32) | (uint32_t)bal;
                __hip_atomic_store(&recpub[widx], v, __ATOMIC_RELAXED,
                                   __HIP_MEMORY_SCOPE_AGENT);
            }
            const float Uo = s ? -65.0f : Un;
            refc = s ? refsteps : refc;
            U = Uo;
            const uint32_t oidx = (uint32_t)(btbase + t) * 1536u + (uint32_t)m;
            __builtin_nontemporal_store(s ? 1.0f : 0.0f, &out[oidx]);
            __builtin_nontemporal_store(Uo, &out[12582912u + oidx]);
        }
        // no second barrier: partials are double-buffered, and no wave can
        // reach step t+2's writes before all waves passed step t+1's barrier.
    }
}

extern "C" void kernel_launch(void* const* d_in, const int* in_sizes, int n_in,
                              void* d_out, int out_size, void* d_ws, size_t ws_size,
                              hipStream_t stream) {
    const float* I   = (const float*)d_in[0];   // input_spikes (32,256,768)
    const float* W   = (const float*)d_in[1];   // weights (1536,1536)
    const float* WF  = (const float*)d_in[2];   // weights_FF (768,1536)
    const float* sf  = (const float*)d_in[3];   // scaling_factors (2,2)
    const float* sfF = (const float*)d_in[4];   // scaling_factors_FF (1,2)
    const int*   ct  = (const int*)d_in[5];     // cell_type_indices (1536)
    // d_in[6] cell_type_indices_FF: all zeros, folded into sfF indexing.

    uint64_t* recpub = (uint64_t*)d_ws;   // 32*256*48*8 = 3,145,728 B

    snn_lif_kernel<<<dim3(512), dim3(768), 0, stream>>>(
        I, W, WF, sf, sfF, ct, (float*)d_out, recpub);
}

// Round 7
// 853.140 us; speedup vs baseline: 1.4973x; 1.0373x over previous
//
#include <hip/hip_runtime.h>
#include <stdint.h>

// Conductance-LIF network, persistent event-driven kernel. Round 13.
//
// Ledger: r6=647us best. r7 (sc0 fast path + gather batch, confounded)=663.
// r8 (wave-autonomous)=3559: row-parallelism mandatory. r9 (2x width)=834:
// L2-throughput term confirmed (~64B/cyc/CU). r10 (reg-queue batch)=750:
// +857 VALU -> +960 step AND proved W-row load batching saves ZERO latency
// (already hidden). r11 (LDS pool)=1196: +2070 VALU -> 1:1 step. r12
// (2 blocks/CU)=792: occupancy 2x, step +22% -> r6's chain consumes
// issue/L2 resources (contention stretches it); idle not exploitable by
// co-residency.
//
// Remaining unexplained term ~3000cyc/step. Diagnosis from r6's inner loop:
// the poll RTT and the row drain SERIALIZE -- each do-while round issues the
// agent-scope poll, waits the full LLC RTT (readlane immediately follows),
// THEN drains arrivals; the next poll only launches after the drain. Words
// arrive spread over a window -> 2-4 rounds/step -> 2-4 serialized RTTs
// (~1500-3000cyc). Never tested in isolation: r7/r10 pipelined the W-row
// loads (provably already hidden), not the POLL.
//
// r13 = r6 BYTE-IDENTICAL except:
//   (1) first poll sample issued BEFORE the FF drain (RTT hides under FF);
//   (2) poll-ahead: each round issues the NEXT sample before processing the
//       current one -- the RTT flies under the drain, consumed next round
//       (final round's extra load is harmless: relaxed, no side effects);
//   (3) ct-masks hoisted to registers (4 LDS reads/step saved, zero risk).
// NOTHING else changed: geometry, gather, partials, barrier, tail, publish,
// protocol all r6. Sync: flag+data in ONE 64-bit word (hi32 = t+1 for step-t
// spikes, lo32 = 32 spike bits), relaxed agent-scope atomics only,
// time-indexed recpub[32][256][48], tags 1..256 never collide with the
// 0xAAAAAAAA ws poison. 256 blocks co-resident; publish for step t precedes
// any wait on step-t words (induction) -> deadlock-free. Block->XCD placement
// is a perf heuristic only, never correctness.

#define ATOMIC_LD(p) __hip_atomic_load((p), __ATOMIC_RELAXED, __HIP_MEMORY_SCOPE_AGENT)

__global__ __launch_bounds__(768) void snn_lif_kernel(
    const float* __restrict__ I,     // [32][256][768] input spikes (0/1)
    const float* __restrict__ W,     // [1536][1536] recurrent weights (row = pre)
    const float* __restrict__ WF,    // [768][1536]  FF weights (row = input)
    const float* __restrict__ sf,    // [2][2] scaling (pre ct, post ct)
    const float* __restrict__ sfF,   // [1][2] FF scaling (post ct)
    const int*   __restrict__ ct,    // [1536] cell type 0/1
    float* __restrict__ out,         // spk [32][256][1536] then volt [...]
    uint64_t* __restrict__ recpub)   // [32][256][48]: (tag<<32)|spike-bits
{
    const int tid = threadIdx.x;
    const int j   = blockIdx.x & 7;    // column slice -> XCD under %8 RR (perf)
    const int b   = blockIdx.x >> 3;   // batch
    const int wv  = tid >> 6;          // wave 0..11
    const int wl  = tid & 63;          // lane

    __shared__ float4   part0[2][12][48];   // rec ct0 partials (dbuf)
    __shared__ float4   part1[2][12][48];   // rec ct1 partials
    __shared__ float4   partF[2][12][48];   // FF partials
    __shared__ uint32_t ctm32_sh[48];       // cell-type bits per 32-neuron word

    // ---- cell-type bitmask via block-wide ballots (2 x 768) ----
    for (int r = 0; r < 2; ++r) {
        int c = ct[r * 768 + tid];
        uint64_t bal = __ballot(c != 0);
        if (wl == 0) {
            ctm32_sh[r * 24 + wv * 2]     = (uint32_t)bal;
            ctm32_sh[r * 24 + wv * 2 + 1] = (uint32_t)(bal >> 32);
        }
    }
    __syncthreads();

    // hoist this wave's 4 word ct-masks to registers (block constants)
    uint32_t cmw[4];
    #pragma unroll
    for (int k = 0; k < 4; ++k) cmw[k] = ctm32_sh[wv * 4 + k];

    // ---- owner-neuron constants (threads 0..191 own neuron m) ----
    const int m = j * 192 + ((tid < 192) ? tid : 0);
    const int   myct = ct[m];
    const float s0m  = sf[myct];
    const float s1m  = sf[2 + myct];
    const float sFm  = sfF[myct];
    const float lc   = (myct == 0) ? (1.0f / 200.0f) : (1.0f / 100.0f);
    const float refsteps = (myct == 0) ? 2.0f : 1.0f;
    const float ar0 = expf(-1.0f / 0.5f),  ad0 = expf(-1.0f / 2.0f);
    const float ar1 = expf(-1.0f / 2.0f),  ad1 = expf(-1.0f / 100.0f);
    const float ar2 = expf(-1.0f / 0.5f),  ad2 = expf(-1.0f / 5.0f);
    const float arF = expf(-1.0f / 0.5f),  adF = expf(-1.0f / 2.0f);

    float U = -65.0f, refc = 0.0f;
    float x0 = 0, g0 = 0, x1 = 0, g1 = 0, x2 = 0, g2 = 0, xF = 0, gF = 0;

    const int  btbase  = b * 256;
    const bool gl      = (wl < 48);                         // gather lane
    const uint32_t colbase = (uint32_t)(j * 192 + wl * 4);  // float offset in row

    // initial FF mask: wave wv ballots inputs wv*64..wv*64+63 of I[b,0,:]
    uint64_t fmask;
    {
        float iv = __builtin_nontemporal_load(
            &I[(uint32_t)btbase * 768u + (uint32_t)tid]);
        fmask = __ballot(iv > 0.5f);
    }

    for (int t = 0; t < 256; ++t) {
        // (1) issue the FIRST poll sample EARLY: its RTT hides under the FF
        // drain below (consumed only at the rec loop's first iteration)
        const uint32_t pbase = (uint32_t)(btbase + t - 1) * 48u + (uint32_t)(wv * 4);
        uint64_t pvcur = 0;
        if (t > 0 && wl < 4)
            pvcur = ATOMIC_LD(&recpub[pbase + (uint32_t)wl]);

        // prefetch next-step input (consumed by the ballot after the gather)
        float ivn = 0.0f;
        if (t < 255)
            ivn = __builtin_nontemporal_load(
                &I[(uint32_t)(btbase + t + 1) * 768u + (uint32_t)tid]);

        float4 a0 = make_float4(0.f, 0.f, 0.f, 0.f);
        float4 a1 = a0, aF = a0;

        // ---- FF rows (always ready; fmask is this wave's own ballot) ----
        {
            uint64_t mm = fmask;   // wave-uniform
            while (mm) {
                const int bit = __builtin_ctzll(mm);
                mm &= mm - 1;
                const uint32_t row = (uint32_t)(wv * 64 + bit);
                if (gl) {
                    const float4 w = *(const float4*)(WF + row * 1536u + colbase);
                    aF.x += w.x; aF.y += w.y; aF.z += w.z; aF.w += w.w;
                }
            }
        }

        // ---- poll 4 rec words; POLL-AHEAD: next sample issued before the
        // current one is processed, so its RTT overlaps the drain ----
        if (t > 0) {
            uint32_t ready = 0;
            do {
                // (2) issue next sample NOW; consumed next iteration. The
                // drain below uses pvcur only -> no dependency, the load
                // flies while rows are gathered.
                uint64_t pvnext = 0;
                if (wl < 4)
                    pvnext = ATOMIC_LD(&recpub[pbase + (uint32_t)wl]);

                const uint32_t plo = (uint32_t)pvcur;
                const uint32_t phi = (uint32_t)(pvcur >> 32);
                #pragma unroll
                for (int k = 0; k < 4; ++k) {
                    if (ready & (1u << k)) continue;
                    const uint32_t tg = (uint32_t)__builtin_amdgcn_readlane(phi, k);
                    if (tg != (uint32_t)t) continue;      // not published yet
                    ready |= 1u << k;
                    uint32_t bits = (uint32_t)__builtin_amdgcn_readlane(plo, k);
                    const uint32_t cm   = cmw[k];
                    const uint32_t word = (uint32_t)(wv * 4 + k);
                    while (bits) {                         // wave-uniform row loop
                        const int bit = __builtin_ctz(bits);
                        bits &= bits - 1;
                        const uint32_t row = word * 32u + (uint32_t)bit;
                        if (gl) {
                            const float4 w = *(const float4*)(W + row * 1536u + colbase);
                            if ((cm >> bit) & 1u) {
                                a1.x += w.x; a1.y += w.y; a1.z += w.z; a1.w += w.w;
                            } else {
                                a0.x += w.x; a0.y += w.y; a0.z += w.z; a0.w += w.w;
                            }
                        }
                    }
                }
                pvcur = pvnext;
            } while (ready != 0xFu);
        }

        const int buf = t & 1;
        if (gl) {
            part0[buf][wv][wl] = a0;
            part1[buf][wv][wl] = a1;
            partF[buf][wv][wl] = aF;
        }
        fmask = __ballot(ivn > 0.5f);   // FF mask for step t+1 (per-wave register)
        __syncthreads();                // partials of ALL waves visible

        // ---- tail (threads 0..191): reduce, LIF, publish FIRST, store ----
        if (tid < 192) {
            const float* p0 = (const float*)&part0[buf][0][0];
            const float* p1 = (const float*)&part1[buf][0][0];
            const float* pF = (const float*)&partF[buf][0][0];
            float z0s = 0.f, z1s = 0.f, zFs = 0.f;
            #pragma unroll
            for (int k = 0; k < 12; ++k) {
                z0s += p0[k * 192 + tid];
                z1s += p1[k * 192 + tid];
                zFs += pF[k * 192 + tid];
            }
            z0s *= s0m; z1s *= s1m; zFs *= sFm;
            x0 = ar0 * x0 + z0s;  g0 = ad0 * g0 + x0;   // syn0 (pre ct0)
            x1 = ar1 * x1 + z0s;  g1 = ad1 * g1 + x1;   // syn1 (pre ct0, same z0)
            x2 = ar2 * x2 + z1s;  g2 = ad2 * g2 + x2;   // syn2 (pre ct1)
            xF = arF * xF + zFs;  gF = adF * gF + xF;   // feed-forward
            const float gtot = g0 + 0.5f * g1 + g2 + gF;   // gbar=[1,.5,1], FF 1
            const float gE   = -70.0f * g2;                // gbar*Erev=[0,0,-70], FF 0
            const float Isyn = gE - gtot * U;
            float Un = U + lc * (10.0f * (-65.0f - U) + Isyn);
            if (refc > 0.0f) Un = -65.0f;
            refc = fmaxf(refc - 1.0f, 0.0f);
            const bool s = (Un - (-50.0f)) >= 0.0f;
            // publish ASAP: waves 0..2 cover 64 consecutive neurons each;
            // lanes 0/32 store (tag<<32)|half — flag and data in one word.
            const uint64_t bal = __ballot(s);
            if (wl == 0 || wl == 32) {
                const uint32_t half = (wl == 0) ? (uint32_t)bal : (uint32_t)(bal >> 32);
                const uint32_t word = (uint32_t)(j * 6 + wv * 2) + (wl == 32 ? 1u : 0u);
                const uint32_t widx = (uint32_t)(btbase + t) * 48u + word;
                const uint64_t v = ((uint64_t)(uint32_t)(t + 1) << 32) | half;
                __hip_atomic_store(&recpub[widx], v, __ATOMIC_RELAXED,
                                   __HIP_MEMORY_SCOPE_AGENT);
            }
            const float Uo = s ? -65.0f : Un;
            refc = s ? refsteps : refc;
            U = Uo;
            const uint32_t oidx = (uint32_t)(btbase + t) * 1536u + (uint32_t)m;
            __builtin_nontemporal_store(s ? 1.0f : 0.0f, &out[oidx]);
            __builtin_nontemporal_store(Uo, &out[12582912u + oidx]);
        }
        // no second barrier: partials are double-buffered, and no wave can
        // reach step t+2's writes before all waves passed step t+1's barrier.
    }
}

extern "C" void kernel_launch(void* const* d_in, const int* in_sizes, int n_in,
                              void* d_out, int out_size, void* d_ws, size_t ws_size,
                              hipStream_t stream) {
    const float* I   = (const float*)d_in[0];   // input_spikes (32,256,768)
    const float* W   = (const float*)d_in[1];   // weights (1536,1536)
    const float* WF  = (const float*)d_in[2];   // weights_FF (768,1536)
    const float* sf  = (const float*)d_in[3];   // scaling_factors (2,2)
    const float* sfF = (const float*)d_in[4];   // scaling_factors_FF (1,2)
    const int*   ct  = (const int*)d_in[5];     // cell_type_indices (1536)
    // d_in[6] cell_type_indices_FF: all zeros, folded into sfF indexing.

    uint64_t* recpub = (uint64_t*)d_ws;   // 32*256*48*8 = 3,145,728 B

    snn_lif_kernel<<<dim3(256), dim3(768), 0, stream>>>(
        I, W, WF, sf, sfF, ct, (float*)d_out, recpub);
}

// Round 8
// 782.731 us; speedup vs baseline: 1.6319x; 1.0900x over previous
//
#include <hip/hip_runtime.h>
#include <stdint.h>

// Conductance-LIF network, persistent event-driven kernel. Round 14.
//
// Ledger: r6=647us best(dispatch). r7 sc0-dual-path=663 null. r8 wave-
// autonomous=3559 (row-parallelism mandatory). r9 2x width=834 (L2-throughput
// term ~50-64B/cyc/CU confirmed). r10 reg-queue=750 (+VALU -> +step 1:1; W-row
// load batching saves 0 -> latency already hidden by 12-wave TLP). r11 LDS
// pool=1196 (same 1:1). r12 2 blocks/CU=792 (occupancy 2x, step +22%:
// contention, idle not fillable). r13 consumer poll-ahead=752 (+stale
// detection +LLC poll flood: FETCH +12MB, VALU DOWN, time UP -> poll traffic
// volume is a real global term).
//
// r14 attacks the one untried mechanism: SAMPLING. r6's consumers each poll
// the LLC at a period of RTT+drain (~900cyc) and burn 12 wave-polls/block;
// detection phase-aligns to each consumer's own round (late words cost up to
// a full round).
//   * 13th wave (block=832 thr) = dedicated POLLER: one load instr samples
//     all 48 words (lanes 0..47), forwards fresh ones (tag==t) to an LDS
//     mailbox mb[48]. LLC poll traffic /12. Sampling period = pure RTT.
//   * 12 gather waves: r6 word-ownership and drain VERBATIM, but spin on
//     LDS mb (~150cyc period, zero LLC traffic).
//   * tail writes its own 6 published words DIRECTLY to mb at publish time:
//     own-block words (the first needed) skip the LLC RTT entirely.
//   * termination: gather wave increments LDS dc[buf] when its 4 words are
//     detected; poller exits at dc==12; dc dbuf + post-barrier reset.
//     Mailbox needs no per-step clear: tags gate freshness (stale tag never
//     matches), overwrites are idempotent (same value).
// Everything else r6 VERBATIM: geometry (8 slices x 192 cols, j=blockIdx&7
// XCD affinity - perf only), gl-guarded 48-lane float4 gather, dbuf LDS
// partials, ONE barrier, tail reduce + LIF + publish-first.
// Global protocol unchanged (proven r6): flag+data in ONE 64-bit word
// (hi32 = t+1 for step-t spikes, lo32 = 32 spike bits), relaxed agent-scope
// atomics only, time-indexed recpub[32][256][48], tags 1..256 never collide
// with 0xAAAAAAAA ws poison. 256 blocks co-resident; publish for step t
// precedes any wait on step-t words (induction) -> deadlock-free. The poller
// waits only on ITS OWN block's waves (all resident) -> no new dependency.

#define ATOMIC_LD(p)   __hip_atomic_load((p), __ATOMIC_RELAXED, __HIP_MEMORY_SCOPE_AGENT)
#define LDS_LD32(p)    __hip_atomic_load((p), __ATOMIC_RELAXED, __HIP_MEMORY_SCOPE_WORKGROUP)
#define LDS_ST32(p, v) __hip_atomic_store((p), (v), __ATOMIC_RELAXED, __HIP_MEMORY_SCOPE_WORKGROUP)
#define LDS_LD64(p)    __hip_atomic_load((p), __ATOMIC_RELAXED, __HIP_MEMORY_SCOPE_WORKGROUP)
#define LDS_ST64(p, v) __hip_atomic_store((p), (v), __ATOMIC_RELAXED, __HIP_MEMORY_SCOPE_WORKGROUP)

__global__ __launch_bounds__(832) void snn_lif_kernel(
    const float* __restrict__ I,     // [32][256][768] input spikes (0/1)
    const float* __restrict__ W,     // [1536][1536] recurrent weights (row = pre)
    const float* __restrict__ WF,    // [768][1536]  FF weights (row = input)
    const float* __restrict__ sf,    // [2][2] scaling (pre ct, post ct)
    const float* __restrict__ sfF,   // [1][2] FF scaling (post ct)
    const int*   __restrict__ ct,    // [1536] cell type 0/1
    float* __restrict__ out,         // spk [32][256][1536] then volt [...]
    uint64_t* __restrict__ recpub)   // [32][256][48]: (tag<<32)|spike-bits
{
    const int tid = threadIdx.x;
    const int j   = blockIdx.x & 7;    // column slice -> XCD under %8 RR (perf)
    const int b   = blockIdx.x >> 3;   // batch
    const int wv  = tid >> 6;          // wave 0..12 (12 = poller)
    const int wl  = tid & 63;          // lane

    __shared__ float4   part0[2][12][48];   // rec ct0 partials (dbuf)
    __shared__ float4   part1[2][12][48];   // rec ct1 partials
    __shared__ float4   partF[2][12][48];   // FF partials
    __shared__ uint32_t ctm32_sh[48];       // cell-type bits per 32-neuron word
    __shared__ uint64_t mb_sh[48];          // mailbox: (tag<<32)|bits
    __shared__ int      dc_sh[2];           // per-step detection counter (dbuf)

    // ---- init mailbox (tag 0 never matches t>=1) + counters ----
    if (tid < 48) mb_sh[tid] = 0;
    if (tid == 0) { dc_sh[0] = 0; dc_sh[1] = 0; }

    // ---- cell-type bitmask via ballots (waves 0..11 cover 2 x 768) ----
    for (int r = 0; r < 2; ++r) {
        if (tid < 768) {
            int c = ct[r * 768 + tid];
            uint64_t bal = __ballot(c != 0);
            if (wl == 0) {
                ctm32_sh[r * 24 + wv * 2]     = (uint32_t)bal;
                ctm32_sh[r * 24 + wv * 2 + 1] = (uint32_t)(bal >> 32);
            }
        }
    }
    __syncthreads();

    // hoist this wave's 4 word ct-masks to registers (waves 0..11)
    uint32_t cmw[4] = {0, 0, 0, 0};
    if (wv < 12) {
        #pragma unroll
        for (int k = 0; k < 4; ++k) cmw[k] = ctm32_sh[wv * 4 + k];
    }

    // ---- owner-neuron constants (threads 0..191 own neuron m) ----
    const int m = j * 192 + ((tid < 192) ? tid : 0);
    const int   myct = ct[m];
    const float s0m  = sf[myct];
    const float s1m  = sf[2 + myct];
    const float sFm  = sfF[myct];
    const float lc   = (myct == 0) ? (1.0f / 200.0f) : (1.0f / 100.0f);
    const float refsteps = (myct == 0) ? 2.0f : 1.0f;
    const float ar0 = expf(-1.0f / 0.5f),  ad0 = expf(-1.0f / 2.0f);
    const float ar1 = expf(-1.0f / 2.0f),  ad1 = expf(-1.0f / 100.0f);
    const float ar2 = expf(-1.0f / 0.5f),  ad2 = expf(-1.0f / 5.0f);
    const float arF = expf(-1.0f / 0.5f),  adF = expf(-1.0f / 2.0f);

    float U = -65.0f, refc = 0.0f;
    float x0 = 0, g0 = 0, x1 = 0, g1 = 0, x2 = 0, g2 = 0, xF = 0, gF = 0;

    const int  btbase  = b * 256;
    const bool gl      = (wl < 48);                         // gather lane
    const uint32_t colbase = (uint32_t)(j * 192 + wl * 4);  // float offset in row

    // initial FF mask: wave wv ballots inputs wv*64..wv*64+63 of I[b,0,:]
    uint64_t fmask = 0;
    {
        float iv = 0.0f;
        if (tid < 768)
            iv = __builtin_nontemporal_load(
                &I[(uint32_t)btbase * 768u + (uint32_t)tid]);
        fmask = __ballot(iv > 0.5f);
    }

    for (int t = 0; t < 256; ++t) {
        const int buf = t & 1;

        // prefetch next-step input (consumed by the ballot before the barrier)
        float ivn = 0.0f;
        if (t < 255 && tid < 768)
            ivn = __builtin_nontemporal_load(
                &I[(uint32_t)(btbase + t + 1) * 768u + (uint32_t)tid]);

        if (wv == 12) {
            // ================= POLLER WAVE =================
            // sample all 48 words each round; forward fresh ones to the
            // mailbox; exit when all 12 gather waves have detected (dc==12).
            if (t > 0) {
                const uint32_t pbase = (uint32_t)(btbase + t - 1) * 48u;
                for (;;) {
                    uint64_t pv = 0;
                    if (wl < 48)
                        pv = ATOMIC_LD(&recpub[pbase + (uint32_t)wl]);
                    if (wl < 48 && (uint32_t)(pv >> 32) == (uint32_t)t)
                        LDS_ST64(&mb_sh[wl], pv);
                    if (LDS_LD32(&dc_sh[buf]) == 12) break;
                }
            }
        } else {
            // ================= GATHER WAVES 0..11 =================
            float4 a0 = make_float4(0.f, 0.f, 0.f, 0.f);
            float4 a1 = a0, aF = a0;

            // ---- FF rows (always ready; fmask is this wave's own ballot) ----
            {
                uint64_t mm = fmask;   // wave-uniform
                while (mm) {
                    const int bit = __builtin_ctzll(mm);
                    mm &= mm - 1;
                    const uint32_t row = (uint32_t)(wv * 64 + bit);
                    if (gl) {
                        const float4 w = *(const float4*)(WF + row * 1536u + colbase);
                        aF.x += w.x; aF.y += w.y; aF.z += w.z; aF.w += w.w;
                    }
                }
            }

            // ---- rec: spin on the LDS mailbox; drain each word on arrival ----
            if (t > 0) {
                uint32_t ready = 0;
                do {
                    uint64_t pv = 0;
                    if (wl < 4)
                        pv = LDS_LD64(&mb_sh[wv * 4 + wl]);
                    const uint32_t plo = (uint32_t)pv;
                    const uint32_t phi = (uint32_t)(pv >> 32);
                    #pragma unroll
                    for (int k = 0; k < 4; ++k) {
                        if (ready & (1u << k)) continue;
                        const uint32_t tg = (uint32_t)__builtin_amdgcn_readlane(phi, k);
                        if (tg != (uint32_t)t) continue;      // not arrived yet
                        ready |= 1u << k;
                        uint32_t bits = (uint32_t)__builtin_amdgcn_readlane(plo, k);
                        const uint32_t cm   = cmw[k];
                        const uint32_t word = (uint32_t)(wv * 4 + k);
                        while (bits) {                         // wave-uniform rows
                            const int bit = __builtin_ctz(bits);
                            bits &= bits - 1;
                            const uint32_t row = word * 32u + (uint32_t)bit;
                            if (gl) {
                                const float4 w = *(const float4*)(W + row * 1536u + colbase);
                                if ((cm >> bit) & 1u) {
                                    a1.x += w.x; a1.y += w.y; a1.z += w.z; a1.w += w.w;
                                } else {
                                    a0.x += w.x; a0.y += w.y; a0.z += w.z; a0.w += w.w;
                                }
                            }
                        }
                    }
                } while (ready != 0xFu);
                if (wl == 0) atomicAdd(&dc_sh[buf], 1);   // poller may stop
            }

            if (gl) {
                part0[buf][wv][wl] = a0;
                part1[buf][wv][wl] = a1;
                partF[buf][wv][wl] = aF;
            }
        }

        fmask = __ballot(ivn > 0.5f);   // FF mask for step t+1 (per-wave reg)
        __syncthreads();                // partials of ALL waves visible

        // ---- tail (threads 0..191): reduce, LIF, publish FIRST, store ----
        if (tid < 192) {
            const float* p0 = (const float*)&part0[buf][0][0];
            const float* p1 = (const float*)&part1[buf][0][0];
            const float* pF = (const float*)&partF[buf][0][0];
            float z0s = 0.f, z1s = 0.f, zFs = 0.f;
            #pragma unroll
            for (int k = 0; k < 12; ++k) {
                z0s += p0[k * 192 + tid];
                z1s += p1[k * 192 + tid];
                zFs += pF[k * 192 + tid];
            }
            z0s *= s0m; z1s *= s1m; zFs *= sFm;
            x0 = ar0 * x0 + z0s;  g0 = ad0 * g0 + x0;   // syn0 (pre ct0)
            x1 = ar1 * x1 + z0s;  g1 = ad1 * g1 + x1;   // syn1 (pre ct0, same z0)
            x2 = ar2 * x2 + z1s;  g2 = ad2 * g2 + x2;   // syn2 (pre ct1)
            xF = arF * xF + zFs;  gF = adF * gF + xF;   // feed-forward
            const float gtot = g0 + 0.5f * g1 + g2 + gF;   // gbar=[1,.5,1], FF 1
            const float gE   = -70.0f * g2;                // gbar*Erev=[0,0,-70], FF 0
            const float Isyn = gE - gtot * U;
            float Un = U + lc * (10.0f * (-65.0f - U) + Isyn);
            if (refc > 0.0f) Un = -65.0f;
            refc = fmaxf(refc - 1.0f, 0.0f);
            const bool s = (Un - (-50.0f)) >= 0.0f;
            // publish: LDS mailbox FIRST (own block: zero LLC hops), then
            // the LLC word for the other 7 blocks. Flag+data in one u64.
            const uint64_t bal = __ballot(s);
            if (wl == 0 || wl == 32) {
                const uint32_t half = (wl == 0) ? (uint32_t)bal : (uint32_t)(bal >> 32);
                const uint32_t word = (uint32_t)(j * 6 + wv * 2) + (wl == 32 ? 1u : 0u);
                const uint32_t widx = (uint32_t)(btbase + t) * 48u + word;
                const uint64_t v = ((uint64_t)(uint32_t)(t + 1) << 32) | half;
                LDS_ST64(&mb_sh[word], v);
                __hip_atomic_store(&recpub[widx], v, __ATOMIC_RELAXED,
                                   __HIP_MEMORY_SCOPE_AGENT);
            }
            const float Uo = s ? -65.0f : Un;
            refc = s ? refsteps : refc;
            U = Uo;
            const uint32_t oidx = (uint32_t)(btbase + t) * 1536u + (uint32_t)m;
            __builtin_nontemporal_store(s ? 1.0f : 0.0f, &out[oidx]);
            __builtin_nontemporal_store(Uo, &out[12582912u + oidx]);
        }

        // reset this step's detection counter for reuse at t+2 (post-barrier:
        // all step-t increments done; t+2 increments happen only after the
        // step-(t+1) barrier). Done by an idle poller-wave thread.
        if (tid == 768) LDS_ST32(&dc_sh[buf], 0);
        // no second barrier: partials & dc double-buffered; mailbox is
        // tag-gated (stale tags never match; fresh overwrites idempotent).
    }
}

extern "C" void kernel_launch(void* const* d_in, const int* in_sizes, int n_in,
                              void* d_out, int out_size, void* d_ws, size_t ws_size,
                              hipStream_t stream) {
    const float* I   = (const float*)d_in[0];   // input_spikes (32,256,768)
    const float* W   = (const float*)d_in[1];   // weights (1536,1536)
    const float* WF  = (const float*)d_in[2];   // weights_FF (768,1536)
    const float* sf  = (const float*)d_in[3];   // scaling_factors (2,2)
    const float* sfF = (const float*)d_in[4];   // scaling_factors_FF (1,2)
    const int*   ct  = (const int*)d_in[5];     // cell_type_indices (1536)
    // d_in[6] cell_type_indices_FF: all zeros, folded into sfF indexing.

    uint64_t* recpub = (uint64_t*)d_ws;   // 32*256*48*8 = 3,145,728 B

    snn_lif_kernel<<<dim3(256), dim3(832), 0, stream>>>(
        I, W, WF, sf, sfF, ct, (float*)d_out, recpub);
}